// Round 5
// baseline (440.767 us; speedup 1.0000x reference)
//
#include <hip/hip_runtime.h>
#include <hip/hip_bf16.h>

#define B_ROWS 256
#define S_SUP  65536
#define D_DIM  768
#define QSZ    512
#define NCH    3            // 768 / 256
#define CHUNK_K 256
#define ACH_BYTES 131072    // A chunk: 256 rows * 256 k * 2 B bf16, k-group-major image

typedef short bf16x8 __attribute__((ext_vector_type(8)));
typedef float f32x4  __attribute__((ext_vector_type(4)));
typedef float f32x16 __attribute__((ext_vector_type(16)));

__device__ __forceinline__ bf16x8 cvt8(float4 a, float4 b) {
  bf16x8 r;
  r[0] = (short)(__float_as_uint(a.x) >> 16);
  r[1] = (short)(__float_as_uint(a.y) >> 16);
  r[2] = (short)(__float_as_uint(a.z) >> 16);
  r[3] = (short)(__float_as_uint(a.w) >> 16);
  r[4] = (short)(__float_as_uint(b.x) >> 16);
  r[5] = (short)(__float_as_uint(b.y) >> 16);
  r[6] = (short)(__float_as_uint(b.z) >> 16);
  r[7] = (short)(__float_as_uint(b.w) >> 16);
  return r;
}

__device__ __forceinline__ void gl_lds16(const void* g, void* l) {
  __builtin_amdgcn_global_load_lds(
      (const __attribute__((address_space(1))) unsigned int*)g,
      (__attribute__((address_space(3))) unsigned int*)l, 16, 0, 0);
}

// block-wide sum (float), result broadcast to all 256 threads (4 waves)
__device__ __forceinline__ float block_sum(float v) {
  __shared__ float tmp[4];
  #pragma unroll
  for (int m = 32; m >= 1; m >>= 1) v += __shfl_xor(v, m, 64);
  __syncthreads();
  if ((threadIdx.x & 63) == 0) tmp[threadIdx.x >> 6] = v;
  __syncthreads();
  return tmp[0] + tmp[1] + tmp[2] + tmp[3];
}

__device__ __forceinline__ double block_sum_d(double v) {
  __shared__ double tmp[4];
  #pragma unroll
  for (int m = 32; m >= 1; m >>= 1) v += __shfl_xor(v, m, 64);
  __syncthreads();
  if ((threadIdx.x & 63) == 0) tmp[threadIdx.x >> 6] = v;
  __syncthreads();
  return tmp[0] + tmp[1] + tmp[2] + tmp[3];
}

// ---- kernel 0: zero accumulators ----
__global__ __launch_bounds__(256) void init_kernel(unsigned long long* gmax, double* bden) {
  int t = threadIdx.x;
  gmax[t] = 0ull;
  for (int i = t; i < 3 * B_ROWS; i += 256) bden[i] = 0.0;
}

// ---- kernel 1: augs[j-1] = normalize(V[j]*L); j==0 -> org_bf16 image ----
// A image, chunk c (k in [256c,256c+256)): 128 KB, k-group-major:
// ushort idx = c*65536 + g*2048 + r*8 + e, where g=(k>>3)&31, e=k&7.
// This IS the LDS layout (verbatim gl_lds copy, dense conflict-free b128 reads).
__global__ __launch_bounds__(256) void prep_kernel(const float* __restrict__ V,
                                                   const float* __restrict__ L,
                                                   unsigned short* __restrict__ orgb,
                                                   float* __restrict__ augs) {
  int jb = blockIdx.x;            // 0..1023
  int j = jb >> 8, b = jb & 255;
  int tid = threadIdx.x;
  __shared__ float srow[D_DIM];
  const float* v = V + ((size_t)j * B_ROWS + b) * D_DIM;
  const float* l = L + (size_t)b * D_DIM;
  float p[3]; float ssq = 0.f;
  #pragma unroll
  for (int i = 0; i < 3; ++i) {
    int k = tid + 256 * i;
    p[i] = v[k] * l[k];
    ssq += p[i] * p[i];
  }
  ssq = block_sum(ssq);
  float inv = 1.0f / fmaxf(sqrtf(ssq), 1e-12f);
  if (j == 0) {
    #pragma unroll
    for (int i = 0; i < 3; ++i) srow[tid + 256 * i] = p[i] * inv;
    __syncthreads();
    if (tid < 96) {                       // 96 groups of 8 k
      int k0 = tid * 8;
      float4 f0 = *(const float4*)&srow[k0];
      float4 f1 = *(const float4*)&srow[k0 + 4];
      bf16x8 hv = cvt8(f0, f1);
      int c = k0 >> 8, g = (k0 >> 3) & 31;
      *(bf16x8*)(orgb + c * 65536 + g * 2048 + b * 8) = hv;
    }
  } else {
    float* dst = augs + ((size_t)(j - 1) * B_ROWS + b) * D_DIM;
    #pragma unroll
    for (int i = 0; i < 3; ++i) dst[tid + 256 * i] = p[i] * inv;
  }
}

// ---- kernel 2: sim = org @ sf^T (bf16 MFMA 32x32x16), per-row argmax ----
// BARRIER-FREE k-loop: A (256x256k bf16 = 128 KB) LDS-resident per chunk (3 chunks,
// 2 barriers each = 6 total). B streams global->reg->MFMA directly, 1-ahead prefetch,
// each 128B line touched exactly once. 512 thr = 8 waves; wave owns 32 sf rows (cols),
// all 256 output rows (acc 8 x f32x16). Grid 256 = 1 block/CU, 2 waves/SIMD.
__global__ __launch_bounds__(512, 2) void sim_argmax_kernel(const unsigned short* __restrict__ orgb,
                                                            const float* __restrict__ sf,
                                                            unsigned long long* __restrict__ gmax) {
  const int tid = threadIdx.x;
  const int w   = tid >> 6;           // wave 0..7
  const int l   = tid & 63;
  const int h   = l >> 5;             // half 0/1 (k-slice select)
  const int c31 = l & 31;
  const int s0  = blockIdx.x * 256;
  const int myrow = s0 + w * 32 + c31;   // sf row == output col this lane owns

  __shared__ __align__(16) char smem[ACH_BYTES];   // 128 KB

  f32x16 accs[8];
  #pragma unroll
  for (int t = 0; t < 8; ++t)
    #pragma unroll
    for (int r = 0; r < 16; ++r) accs[t][r] = 0.f;

  const char* sfb = (const char*)sf + (size_t)myrow * 3072 + h * 32;
  const char* agbase = (const char*)orgb + tid * 16;
  char* adst = smem + tid * 16;

  for (int c = 0; c < NCH; ++c) {
    // stage A chunk: 128 KB verbatim, 16 gl_lds x 16 B per thread
    {
      const char* g = agbase + c * ACH_BYTES;
      #pragma unroll
      for (int i = 0; i < 16; ++i)
        gl_lds16(g + i * 8192, adst + i * 8192);
    }
    __syncthreads();

    const char* brow = sfb + c * 1024;
    float4 nb0 = *(const float4*)(brow);
    float4 nb1 = *(const float4*)(brow + 16);
    #pragma unroll
    for (int ks = 0; ks < 16; ++ks) {
      float4 cb0 = nb0, cb1 = nb1;
      if (ks < 15) {
        nb0 = *(const float4*)(brow + (ks + 1) * 64);
        nb1 = *(const float4*)(brow + (ks + 1) * 64 + 16);
      }
      bf16x8 bf = cvt8(cb0, cb1);
      // A frags: plane g = 2*ks+h (4 KB = 256 rows x 16 B), rows rt*32 + c31
      const char* ab = smem + (ks * 2 + h) * 4096 + c31 * 16;
      #pragma unroll
      for (int rt = 0; rt < 8; ++rt) {
        bf16x8 af = *(const bf16x8*)(ab + rt * 512);
        accs[rt] = __builtin_amdgcn_mfma_f32_32x32x16_bf16(af, bf, accs[rt], 0, 0, 0);
      }
    }
    __syncthreads();   // all reads of this A chunk done before restaging
  }

  // epilogue: overlay reduction arrays on smem
  float* smax = (float*)smem;            // [8][256]
  int*   sidx = (int*)(smem + 8192);
  #pragma unroll
  for (int rt = 0; rt < 8; ++rt) {
    #pragma unroll
    for (int rg = 0; rg < 16; ++rg) {
      float v = accs[rt][rg];
      int idx = myrow;
      #pragma unroll
      for (int m = 1; m < 32; m <<= 1) {   // reduce 32 col-lanes (stays within half)
        float ov = __shfl_xor(v, m, 64);
        int   oi = __shfl_xor(idx, m, 64);
        if (ov > v || (ov == v && oi < idx)) { v = ov; idx = oi; }
      }
      if (c31 == 0) {
        int row = rt * 32 + (rg & 3) + 8 * (rg >> 2) + 4 * h;  // C/D: m74/m101
        smax[w * 256 + row] = v;
        sidx[w * 256 + row] = idx;
      }
    }
  }
  __syncthreads();
  if (tid < 256) {
    int row = tid;
    float v = smax[row]; int idx = sidx[row];
    #pragma unroll
    for (int w2 = 1; w2 < 8; ++w2) {
      float ov = smax[w2 * 256 + row]; int oi = sidx[w2 * 256 + row];
      if (ov > v || (ov == v && oi < idx)) { v = ov; idx = oi; }
    }
    unsigned u = __float_as_uint(v);
    unsigned key = (u & 0x80000000u) ? ~u : (u | 0x80000000u);
    unsigned long long packed = ((unsigned long long)key << 32) |
                                (unsigned long long)(0xFFFFFFFFu - (unsigned)idx);
    if (packed > gmax[row]) atomicMax(gmax + row, packed);  // stale read safe
  }
}

// ---- kernel 3: nn = normalize(sf[nn_idx]); nnT; num = dot(nn, augs[0][b]) / T ----
__global__ __launch_bounds__(256) void nn_kernel(const unsigned long long* __restrict__ gmax,
                                                 const float* __restrict__ sf,
                                                 const float* __restrict__ augs,
                                                 float* __restrict__ nn,
                                                 float* __restrict__ nnT,
                                                 float* __restrict__ num) {
  int b = blockIdx.x, tid = threadIdx.x;
  int idx = (int)(0xFFFFFFFFu - (unsigned)(gmax[b] & 0xFFFFFFFFull));
  const float* row = sf + (size_t)idx * D_DIM;
  float p[3]; float ssq = 0.f;
  #pragma unroll
  for (int i = 0; i < 3; ++i) { p[i] = row[tid + 256 * i]; ssq += p[i] * p[i]; }
  ssq = block_sum(ssq);
  float inv = 1.0f / fmaxf(sqrtf(ssq), 1e-12f);
  const float* a0 = augs + (size_t)b * D_DIM;    // augs[0][b]
  float dot = 0.f;
  #pragma unroll
  for (int i = 0; i < 3; ++i) {
    int k = tid + 256 * i;
    float nv = p[i] * inv;
    nn[(size_t)b * D_DIM + k] = nv;
    nnT[(size_t)k * B_ROWS + b] = nv;
    dot += nv * a0[k];
  }
  dot = block_sum(dot);
  if (tid == 0) num[b] = dot * 10.0f;            // 1/TEMP = 10
}

// ---- kernel 4: batch_den[j][b] += sum_i exp(10*dot(nn_b, aug_ji)) (double acc) ----
__global__ __launch_bounds__(256) void bden_kernel(const float* __restrict__ augs,
                                                   const float* __restrict__ nnT,
                                                   double* __restrict__ bden) {
  int jc = blockIdx.x;                 // 0..191
  int j = jc >> 6, c = jc & 63;
  int i0 = c * 4;
  __shared__ float s_aug[4 * D_DIM];
  const float* src = augs + ((size_t)j * B_ROWS + i0) * D_DIM;
  for (int idx = threadIdx.x; idx < 4 * D_DIM; idx += 256) s_aug[idx] = src[idx];
  __syncthreads();
  int b = threadIdx.x;
  float a0 = 0.f, a1 = 0.f, a2 = 0.f, a3 = 0.f;
  for (int k = 0; k < D_DIM; ++k) {
    float nv = nnT[(size_t)k * B_ROWS + b];
    a0 += nv * s_aug[k];
    a1 += nv * s_aug[D_DIM + k];
    a2 += nv * s_aug[2 * D_DIM + k];
    a3 += nv * s_aug[3 * D_DIM + k];
  }
  double v = exp((double)a0 * 10.0) + exp((double)a1 * 10.0) +
             exp((double)a2 * 10.0) + exp((double)a3 * 10.0);
  atomicAdd(&bden[j * B_ROWS + b], v);
}

// ---- kernel 5: GPS-filtered queue denominator (16 lanes per row, double exp-sum) ----
__global__ __launch_bounds__(256) void queue_kernel(const float* __restrict__ gps,
                                                    const float* __restrict__ sgps,
                                                    const float* __restrict__ sf,
                                                    const float* __restrict__ nn,
                                                    double* __restrict__ qden) {
  int b = blockIdx.x, tid = threadIdx.x;
  int w = tid >> 6, lane = tid & 63;
  __shared__ int qidx[QSZ];
  __shared__ int s_count;
  __shared__ int s_wcnt[4];
  __shared__ __align__(16) float s_nn[D_DIM];
  __shared__ double s_gsum[16];
  for (int k = tid; k < D_DIM; k += 256) s_nn[k] = nn[(size_t)b * D_DIM + k];
  if (tid == 0) s_count = 0;
  __syncthreads();

  const float r = 0.017453292519943295f;
  float lat1 = gps[b * 2 + 0] * r, lon1 = gps[b * 2 + 1] * r;
  float cl1 = cosf(lat1);
  int base = 0;
  while (true) {
    int count = s_count;
    if (count >= QSZ || base >= S_SUP) break;
    int s = base + tid;
    float lat2 = sgps[s * 2 + 0] * r, lon2 = sgps[s * 2 + 1] * r;
    float sdlat = sinf((lat2 - lat1) * 0.5f);
    float sdlon = sinf((lon2 - lon1) * 0.5f);
    float a = sdlat * sdlat + cl1 * cosf(lat2) * sdlon * sdlon;
    a = fminf(fmaxf(a, 0.f), 1.f);
    float d = 2.0f * 6371.0088f * asinf(sqrtf(a));
    bool valid = d > 25.0f;

    unsigned long long m = __ballot(valid);
    int wcnt = __popcll(m);
    if (lane == 0) s_wcnt[w] = wcnt;
    __syncthreads();
    int wbase = count;
    for (int i = 0; i < w; ++i) wbase += s_wcnt[i];
    int pos = wbase + __popcll(m & ((1ull << lane) - 1ull));
    if (valid && pos < QSZ) qidx[pos] = s;
    __syncthreads();
    if (tid == 0) {
      int total = s_wcnt[0] + s_wcnt[1] + s_wcnt[2] + s_wcnt[3];
      s_count = min(QSZ, count + total);
    }
    base += 256;
    __syncthreads();
  }
  int count = s_count;

  // phase 2: 16 lanes per row, 16 rows in flight per block
  int g  = lane >> 4;                  // group 0..3 within wave
  int l2 = lane & 15;
  double acc = 0.0;
  const float4* nn4 = (const float4*)s_nn;
  for (int q = w * 4 + g; q < count; q += 16) {
    const float4* row = (const float4*)(sf + (size_t)qidx[q] * D_DIM);
    float dot = 0.f;
    #pragma unroll
    for (int i = 0; i < 12; ++i) {
      float4 a = row[l2 + 16 * i];
      float4 nv = nn4[l2 + 16 * i];
      dot += a.x * nv.x + a.y * nv.y + a.z * nv.z + a.w * nv.w;
    }
    #pragma unroll
    for (int m2 = 8; m2 >= 1; m2 >>= 1) dot += __shfl_xor(dot, m2, 16);
    if (l2 == 0) acc += exp((double)dot * 10.0);
  }
  if (l2 == 0) s_gsum[w * 4 + g] = acc;
  __syncthreads();
  if (tid == 0) {
    double t = (double)(QSZ - count);
    #pragma unroll
    for (int i = 0; i < 16; ++i) t += s_gsum[i];
    qden[b] = t;
  }
}

// ---- kernel 6: final scalar loss (double) ----
__global__ __launch_bounds__(256) void loss_kernel(const float* __restrict__ num,
                                                   const double* __restrict__ bden,
                                                   const double* __restrict__ qden,
                                                   float* __restrict__ out) {
  int b = threadIdx.x;
  double q = qden[b];
  double n = (double)num[b];
  double t = 0.0;
  #pragma unroll
  for (int j = 0; j < 3; ++j) t += n - log(bden[j * B_ROWS + b] + q);
  t = block_sum_d(t);
  if (b == 0) out[0] = (float)(-t / 256.0);
}

extern "C" void kernel_launch(void* const* d_in, const int* in_sizes, int n_in,
                              void* d_out, int out_size, void* d_ws, size_t ws_size,
                              hipStream_t stream) {
  const float* V    = (const float*)d_in[0];   // (4,256,768)
  const float* L    = (const float*)d_in[1];   // (256,768)
  const float* gps  = (const float*)d_in[2];   // (256,2)
  const float* sf   = (const float*)d_in[3];   // (65536,768)
  const float* sgps = (const float*)d_in[4];   // (65536,2)
  float* out = (float*)d_out;

  char* ws = (char*)d_ws;
  size_t off = 0;
  unsigned short* orgb = (unsigned short*)(ws + off); off += 393216;  // 3*128KB bf16 image
  float* augs = (float*)(ws + off); off += 2359296;                   // 3*256*768*4
  float* nn   = (float*)(ws + off); off += 786432;
  float* nnT  = (float*)(ws + off); off += 786432;
  float* num  = (float*)(ws + off); off += 1024;                      // 256*4
  double* bden = (double*)(ws + off); off += 6144;                    // 3*256*8
  double* qden = (double*)(ws + off); off += 2048;                    // 256*8
  unsigned long long* gmax = (unsigned long long*)(ws + off); off += 2048;

  init_kernel<<<1, 256, 0, stream>>>(gmax, bden);
  prep_kernel<<<1024, 256, 0, stream>>>(V, L, orgb, augs);
  sim_argmax_kernel<<<S_SUP / 256, 512, 0, stream>>>(orgb, sf, gmax);
  nn_kernel<<<B_ROWS, 256, 0, stream>>>(gmax, sf, augs, nn, nnT, num);
  bden_kernel<<<192, 256, 0, stream>>>(augs, nnT, bden);
  queue_kernel<<<B_ROWS, 256, 0, stream>>>(gps, sgps, sf, nn, qden);
  loss_kernel<<<1, 256, 0, stream>>>(num, bden, qden, out);
}

// Round 6
// 405.400 us; speedup vs baseline: 1.0872x; 1.0872x over previous
//
#include <hip/hip_runtime.h>
#include <hip/hip_bf16.h>

#define B_ROWS 256
#define S_SUP  65536
#define D_DIM  768
#define QSZ    512
#define NKT    12           // 768 / 64 K-steps
#define ASTEP  32768        // A per K-step: 8 planes * 256 rows * 16 B
#define BSTEP  16384        // B per K-step: 8 planes * 128 cols * 16 B
#define BBASE  65536        // B LDS base (after A double buffer)

typedef short bf16x8 __attribute__((ext_vector_type(8)));
typedef float f32x4  __attribute__((ext_vector_type(4)));
typedef float f32x16 __attribute__((ext_vector_type(16)));

__device__ __forceinline__ bf16x8 cvt8(float4 a, float4 b) {
  bf16x8 r;
  r[0] = (short)(__float_as_uint(a.x) >> 16);
  r[1] = (short)(__float_as_uint(a.y) >> 16);
  r[2] = (short)(__float_as_uint(a.z) >> 16);
  r[3] = (short)(__float_as_uint(a.w) >> 16);
  r[4] = (short)(__float_as_uint(b.x) >> 16);
  r[5] = (short)(__float_as_uint(b.y) >> 16);
  r[6] = (short)(__float_as_uint(b.z) >> 16);
  r[7] = (short)(__float_as_uint(b.w) >> 16);
  return r;
}

// block-wide sum (float), result broadcast to all 256 threads (4 waves)
__device__ __forceinline__ float block_sum(float v) {
  __shared__ float tmp[4];
  #pragma unroll
  for (int m = 32; m >= 1; m >>= 1) v += __shfl_xor(v, m, 64);
  __syncthreads();
  if ((threadIdx.x & 63) == 0) tmp[threadIdx.x >> 6] = v;
  __syncthreads();
  return tmp[0] + tmp[1] + tmp[2] + tmp[3];
}

__device__ __forceinline__ double block_sum_d(double v) {
  __shared__ double tmp[4];
  #pragma unroll
  for (int m = 32; m >= 1; m >>= 1) v += __shfl_xor(v, m, 64);
  __syncthreads();
  if ((threadIdx.x & 63) == 0) tmp[threadIdx.x >> 6] = v;
  __syncthreads();
  return tmp[0] + tmp[1] + tmp[2] + tmp[3];
}

// ---- kernel 0: zero accumulators ----
__global__ __launch_bounds__(256) void init_kernel(unsigned long long* gmax, double* bden) {
  int t = threadIdx.x;
  gmax[t] = 0ull;
  for (int i = t; i < 3 * B_ROWS; i += 256) bden[i] = 0.0;
}

// ---- kernel 1: augs[j-1] = normalize(V[j]*L); j==0 -> org_bf16 image ----
// A image, K-step kt (k in [64kt,64kt+64)): 32 KB, plane-major:
// ushort idx = kt*16384 + g*2048 + r*8 + e, where g=(k>>3)&7, e=k&7.
// This IS the LDS layout (verbatim copy; dense conflict-free b128 reads).
__global__ __launch_bounds__(256) void prep_kernel(const float* __restrict__ V,
                                                   const float* __restrict__ L,
                                                   unsigned short* __restrict__ orgb,
                                                   float* __restrict__ augs) {
  int jb = blockIdx.x;            // 0..1023
  int j = jb >> 8, b = jb & 255;
  int tid = threadIdx.x;
  __shared__ float srow[D_DIM];
  const float* v = V + ((size_t)j * B_ROWS + b) * D_DIM;
  const float* l = L + (size_t)b * D_DIM;
  float p[3]; float ssq = 0.f;
  #pragma unroll
  for (int i = 0; i < 3; ++i) {
    int k = tid + 256 * i;
    p[i] = v[k] * l[k];
    ssq += p[i] * p[i];
  }
  ssq = block_sum(ssq);
  float inv = 1.0f / fmaxf(sqrtf(ssq), 1e-12f);
  if (j == 0) {
    #pragma unroll
    for (int i = 0; i < 3; ++i) srow[tid + 256 * i] = p[i] * inv;
    __syncthreads();
    if (tid < 96) {                       // 96 groups of 8 k
      int k0 = tid * 8;
      float4 f0 = *(const float4*)&srow[k0];
      float4 f1 = *(const float4*)&srow[k0 + 4];
      bf16x8 hv = cvt8(f0, f1);
      int c = k0 >> 6, g = (k0 >> 3) & 7;
      *(bf16x8*)(orgb + c * 16384 + g * 2048 + b * 8) = hv;
    }
  } else {
    float* dst = augs + ((size_t)(j - 1) * B_ROWS + b) * D_DIM;
    #pragma unroll
    for (int i = 0; i < 3; ++i) dst[tid + 256 * i] = p[i] * inv;
  }
}

// ---- kernel 2: sim = org @ sf^T (bf16 MFMA 32x32x16), per-row argmax ----
// Pipelined reg-staged GEMM, NO vmcnt drains: raw s_barrier + lgkmcnt(0) only.
// Tile BM=256 x BN=128, BK=64, 512 thr = 8 waves (wr=w>>1 64-row band, wc=w&1
// 64-col band; wave out 64x64 = 4 x 32x32 acc). LDS 96 KB double-buffered
// (A 2x32K verbatim image, B 2x16K bf16 with slot = s^g XOR swizzle).
// Per step: issue next global loads -> compute from LDS -> cvt+write next buf
// (implicit vmcnt wait lands here, after MFMAs) -> lgkmcnt(0)+barrier.
__global__ __launch_bounds__(512, 2) void sim_argmax_kernel(const unsigned short* __restrict__ orgb,
                                                            const float* __restrict__ sf,
                                                            unsigned long long* __restrict__ gmax) {
  const int tid = threadIdx.x;
  const int w   = tid >> 6;           // wave 0..7
  const int l   = tid & 63;
  const int h   = l >> 5;             // half 0/1 (k-slice select)
  const int c31 = l & 31;
  const int wr  = w >> 1;             // row band (64 rows)
  const int wc  = w & 1;              // col band (64 cols)
  const int s0  = blockIdx.x * 128;

  __shared__ __align__(16) char smem[98304];

  f32x16 acc[4];                      // [rt*2+nt]
  #pragma unroll
  for (int t = 0; t < 4; ++t)
    #pragma unroll
    for (int r = 0; r < 16; ++r) acc[t][r] = 0.f;

  // ---- staging assignments ----
  // A: thread t copies 64 B of the 32 KB step-image: 4 x b128 at t*16 + i*8192
  const char* agbase = (const char*)orgb + tid * 16;
  // B: thread t -> col s = t>>2, k-quarter q = t&3 (16 k = groups 2q, 2q+1)
  const int bsr = tid >> 2;
  const int bq  = tid & 3;
  const float* bgbase = sf + (size_t)(s0 + bsr) * D_DIM + bq * 16;
  const int bg0 = bq * 2;
  char* bdst0 = smem + BBASE + bg0 * 2048 + (((bsr ^ bg0) & 127) << 4);
  char* bdst1 = smem + BBASE + (bg0 + 1) * 2048 + (((bsr ^ (bg0 + 1)) & 127) << 4);

  // ---- read-side constants ----
  const int arow0 = (wr * 64 + c31) * 16;          // rt=0 (+32*16 for rt=1)
  const int bcol0 = wc * 64 + c31;                 // nt=0 (+32 for nt=1)

  bf16x8 av0, av1, av2, av3;
  float4 f0, f1, f2, f3;

  // ---- prologue: stage step 0 ----
  {
    const char* ag = agbase;
    av0 = *(const bf16x8*)(ag);
    av1 = *(const bf16x8*)(ag + 8192);
    av2 = *(const bf16x8*)(ag + 16384);
    av3 = *(const bf16x8*)(ag + 24576);
    const float4* bp = (const float4*)bgbase;
    f0 = bp[0]; f1 = bp[1]; f2 = bp[2]; f3 = bp[3];
    char* ad = smem + tid * 16;
    *(bf16x8*)(ad)         = av0;
    *(bf16x8*)(ad + 8192)  = av1;
    *(bf16x8*)(ad + 16384) = av2;
    *(bf16x8*)(ad + 24576) = av3;
    *(bf16x8*)bdst0 = cvt8(f0, f1);
    *(bf16x8*)bdst1 = cvt8(f2, f3);
  }
  asm volatile("s_waitcnt lgkmcnt(0)" ::: "memory");
  __builtin_amdgcn_s_barrier();
  __builtin_amdgcn_sched_barrier(0);

  for (int kt = 0; kt < NKT; ++kt) {
    const int cur = kt & 1;
    // -- issue next step's global loads (stay in flight through compute) --
    if (kt < NKT - 1) {
      const char* ag = agbase + (kt + 1) * ASTEP;
      av0 = *(const bf16x8*)(ag);
      av1 = *(const bf16x8*)(ag + 8192);
      av2 = *(const bf16x8*)(ag + 16384);
      av3 = *(const bf16x8*)(ag + 24576);
      const float4* bp = (const float4*)(bgbase + (size_t)(kt + 1) * 64);
      f0 = bp[0]; f1 = bp[1]; f2 = bp[2]; f3 = bp[3];
    }
    __builtin_amdgcn_sched_barrier(0);

    // -- compute step kt from LDS[cur] --
    const char* abuf = smem + cur * ASTEP;
    const char* bbuf = smem + BBASE + cur * BSTEP;
    #pragma unroll
    for (int ks = 0; ks < 4; ++ks) {
      const int g = ks * 2 + h;
      bf16x8 a0 = *(const bf16x8*)(abuf + g * 4096 + arow0);
      bf16x8 a1 = *(const bf16x8*)(abuf + g * 4096 + arow0 + 512);
      bf16x8 b0 = *(const bf16x8*)(bbuf + g * 2048 + (((bcol0      ) ^ g) & 127) * 16);
      bf16x8 b1 = *(const bf16x8*)(bbuf + g * 2048 + (((bcol0 + 32 ) ^ g) & 127) * 16);
      acc[0] = __builtin_amdgcn_mfma_f32_32x32x16_bf16(a0, b0, acc[0], 0, 0, 0);
      acc[1] = __builtin_amdgcn_mfma_f32_32x32x16_bf16(a0, b1, acc[1], 0, 0, 0);
      acc[2] = __builtin_amdgcn_mfma_f32_32x32x16_bf16(a1, b0, acc[2], 0, 0, 0);
      acc[3] = __builtin_amdgcn_mfma_f32_32x32x16_bf16(a1, b1, acc[3], 0, 0, 0);
    }
    __builtin_amdgcn_sched_barrier(0);

    // -- write next buffer (vmcnt waits happen here), then single barrier --
    if (kt < NKT - 1) {
      const int nxt = cur ^ 1;
      char* ad = smem + nxt * ASTEP + tid * 16;
      *(bf16x8*)(ad)         = av0;
      *(bf16x8*)(ad + 8192)  = av1;
      *(bf16x8*)(ad + 16384) = av2;
      *(bf16x8*)(ad + 24576) = av3;
      char* bd = smem + nxt * BSTEP;
      *(bf16x8*)(bd + (bdst0 - smem)) = cvt8(f0, f1);   // bdst already has BBASE
      *(bf16x8*)(bd + (bdst1 - smem)) = cvt8(f2, f3);
      asm volatile("s_waitcnt lgkmcnt(0)" ::: "memory");
      __builtin_amdgcn_s_barrier();
      __builtin_amdgcn_sched_barrier(0);
    }
  }

  // ---- epilogue: per-row argmax ----
  // last compute read buf1 ([32K,64K) + [80K,96K)); overlay [0,4K) is safe now.
  float* smax = (float*)smem;            // [2][256]
  int*   sidx = (int*)(smem + 2048);
  #pragma unroll
  for (int rt = 0; rt < 2; ++rt) {
    #pragma unroll
    for (int rg = 0; rg < 16; ++rg) {
      float v0 = acc[rt * 2 + 0][rg];
      float v1 = acc[rt * 2 + 1][rg];
      int i0 = s0 + bcol0;
      int i1 = i0 + 32;
      float v; int idx;
      if (v1 > v0) { v = v1; idx = i1; } else { v = v0; idx = i0; }
      #pragma unroll
      for (int m = 1; m < 32; m <<= 1) {   // reduce 32 col-lanes (stays in half)
        float ov = __shfl_xor(v, m, 64);
        int   oi = __shfl_xor(idx, m, 64);
        if (ov > v || (ov == v && oi < idx)) { v = ov; idx = oi; }
      }
      if (c31 == 0) {
        int row = wr * 64 + rt * 32 + (rg & 3) + 8 * (rg >> 2) + 4 * h;  // m74/m101
        smax[wc * 256 + row] = v;
        sidx[wc * 256 + row] = idx;
      }
    }
  }
  __syncthreads();
  if (tid < 256) {
    int b = tid;
    float v  = smax[b];       int idx = sidx[b];
    float ov = smax[256 + b]; int oi  = sidx[256 + b];
    if (ov > v || (ov == v && oi < idx)) { v = ov; idx = oi; }
    unsigned u = __float_as_uint(v);
    unsigned key = (u & 0x80000000u) ? ~u : (u | 0x80000000u);
    unsigned long long packed = ((unsigned long long)key << 32) |
                                (unsigned long long)(0xFFFFFFFFu - (unsigned)idx);
    if (packed > gmax[b]) atomicMax(gmax + b, packed);   // stale read safe
  }
}

// ---- kernel 3: nn = normalize(sf[nn_idx]); nnT; num = dot(nn, augs[0][b]) / T ----
__global__ __launch_bounds__(256) void nn_kernel(const unsigned long long* __restrict__ gmax,
                                                 const float* __restrict__ sf,
                                                 const float* __restrict__ augs,
                                                 float* __restrict__ nn,
                                                 float* __restrict__ nnT,
                                                 float* __restrict__ num) {
  int b = blockIdx.x, tid = threadIdx.x;
  int idx = (int)(0xFFFFFFFFu - (unsigned)(gmax[b] & 0xFFFFFFFFull));
  const float* row = sf + (size_t)idx * D_DIM;
  float p[3]; float ssq = 0.f;
  #pragma unroll
  for (int i = 0; i < 3; ++i) { p[i] = row[tid + 256 * i]; ssq += p[i] * p[i]; }
  ssq = block_sum(ssq);
  float inv = 1.0f / fmaxf(sqrtf(ssq), 1e-12f);
  const float* a0 = augs + (size_t)b * D_DIM;    // augs[0][b]
  float dot = 0.f;
  #pragma unroll
  for (int i = 0; i < 3; ++i) {
    int k = tid + 256 * i;
    float nv = p[i] * inv;
    nn[(size_t)b * D_DIM + k] = nv;
    nnT[(size_t)k * B_ROWS + b] = nv;
    dot += nv * a0[k];
  }
  dot = block_sum(dot);
  if (tid == 0) num[b] = dot * 10.0f;            // 1/TEMP = 10
}

// ---- kernel 4: batch_den[j][b] += sum_i exp(10*dot(nn_b, aug_ji)) (double acc) ----
__global__ __launch_bounds__(256) void bden_kernel(const float* __restrict__ augs,
                                                   const float* __restrict__ nnT,
                                                   double* __restrict__ bden) {
  int jc = blockIdx.x;                 // 0..191
  int j = jc >> 6, c = jc & 63;
  int i0 = c * 4;
  __shared__ float s_aug[4 * D_DIM];
  const float* src = augs + ((size_t)j * B_ROWS + i0) * D_DIM;
  for (int idx = threadIdx.x; idx < 4 * D_DIM; idx += 256) s_aug[idx] = src[idx];
  __syncthreads();
  int b = threadIdx.x;
  float a0 = 0.f, a1 = 0.f, a2 = 0.f, a3 = 0.f;
  for (int k = 0; k < D_DIM; ++k) {
    float nv = nnT[(size_t)k * B_ROWS + b];
    a0 += nv * s_aug[k];
    a1 += nv * s_aug[D_DIM + k];
    a2 += nv * s_aug[2 * D_DIM + k];
    a3 += nv * s_aug[3 * D_DIM + k];
  }
  double v = exp((double)a0 * 10.0) + exp((double)a1 * 10.0) +
             exp((double)a2 * 10.0) + exp((double)a3 * 10.0);
  atomicAdd(&bden[j * B_ROWS + b], v);
}

// ---- kernel 5: GPS-filtered queue denominator (16 lanes per row, double exp-sum) ----
__global__ __launch_bounds__(256) void queue_kernel(const float* __restrict__ gps,
                                                    const float* __restrict__ sgps,
                                                    const float* __restrict__ sf,
                                                    const float* __restrict__ nn,
                                                    double* __restrict__ qden) {
  int b = blockIdx.x, tid = threadIdx.x;
  int w = tid >> 6, lane = tid & 63;
  __shared__ int qidx[QSZ];
  __shared__ int s_count;
  __shared__ int s_wcnt[4];
  __shared__ __align__(16) float s_nn[D_DIM];
  __shared__ double s_gsum[16];
  for (int k = tid; k < D_DIM; k += 256) s_nn[k] = nn[(size_t)b * D_DIM + k];
  if (tid == 0) s_count = 0;
  __syncthreads();

  const float r = 0.017453292519943295f;
  float lat1 = gps[b * 2 + 0] * r, lon1 = gps[b * 2 + 1] * r;
  float cl1 = cosf(lat1);
  int base = 0;
  while (true) {
    int count = s_count;
    if (count >= QSZ || base >= S_SUP) break;
    int s = base + tid;
    float lat2 = sgps[s * 2 + 0] * r, lon2 = sgps[s * 2 + 1] * r;
    float sdlat = sinf((lat2 - lat1) * 0.5f);
    float sdlon = sinf((lon2 - lon1) * 0.5f);
    float a = sdlat * sdlat + cl1 * cosf(lat2) * sdlon * sdlon;
    a = fminf(fmaxf(a, 0.f), 1.f);
    float d = 2.0f * 6371.0088f * asinf(sqrtf(a));
    bool valid = d > 25.0f;

    unsigned long long m = __ballot(valid);
    int wcnt = __popcll(m);
    if (lane == 0) s_wcnt[w] = wcnt;
    __syncthreads();
    int wbase = count;
    for (int i = 0; i < w; ++i) wbase += s_wcnt[i];
    int pos = wbase + __popcll(m & ((1ull << lane) - 1ull));
    if (valid && pos < QSZ) qidx[pos] = s;
    __syncthreads();
    if (tid == 0) {
      int total = s_wcnt[0] + s_wcnt[1] + s_wcnt[2] + s_wcnt[3];
      s_count = min(QSZ, count + total);
    }
    base += 256;
    __syncthreads();
  }
  int count = s_count;

  // phase 2: 16 lanes per row, 16 rows in flight per block
  int g  = lane >> 4;                  // group 0..3 within wave
  int l2 = lane & 15;
  double acc = 0.0;
  const float4* nn4 = (const float4*)s_nn;
  for (int q = w * 4 + g; q < count; q += 16) {
    const float4* row = (const float4*)(sf + (size_t)qidx[q] * D_DIM);
    float dot = 0.f;
    #pragma unroll
    for (int i = 0; i < 12; ++i) {
      float4 a = row[l2 + 16 * i];
      float4 nv = nn4[l2 + 16 * i];
      dot += a.x * nv.x + a.y * nv.y + a.z * nv.z + a.w * nv.w;
    }
    #pragma unroll
    for (int m2 = 8; m2 >= 1; m2 >>= 1) dot += __shfl_xor(dot, m2, 16);
    if (l2 == 0) acc += exp((double)dot * 10.0);
  }
  if (l2 == 0) s_gsum[w * 4 + g] = acc;
  __syncthreads();
  if (tid == 0) {
    double t = (double)(QSZ - count);
    #pragma unroll
    for (int i = 0; i < 16; ++i) t += s_gsum[i];
    qden[b] = t;
  }
}

// ---- kernel 6: final scalar loss (double) ----
__global__ __launch_bounds__(256) void loss_kernel(const float* __restrict__ num,
                                                   const double* __restrict__ bden,
                                                   const double* __restrict__ qden,
                                                   float* __restrict__ out) {
  int b = threadIdx.x;
  double q = qden[b];
  double n = (double)num[b];
  double t = 0.0;
  #pragma unroll
  for (int j = 0; j < 3; ++j) t += n - log(bden[j * B_ROWS + b] + q);
  t = block_sum_d(t);
  if (b == 0) out[0] = (float)(-t / 256.0);
}

extern "C" void kernel_launch(void* const* d_in, const int* in_sizes, int n_in,
                              void* d_out, int out_size, void* d_ws, size_t ws_size,
                              hipStream_t stream) {
  const float* V    = (const float*)d_in[0];   // (4,256,768)
  const float* L    = (const float*)d_in[1];   // (256,768)
  const float* gps  = (const float*)d_in[2];   // (256,2)
  const float* sf   = (const float*)d_in[3];   // (65536,768)
  const float* sgps = (const float*)d_in[4];   // (65536,2)
  float* out = (float*)d_out;

  char* ws = (char*)d_ws;
  size_t off = 0;
  unsigned short* orgb = (unsigned short*)(ws + off); off += 393216;  // 12*32KB bf16 image
  float* augs = (float*)(ws + off); off += 2359296;                   // 3*256*768*4
  float* nn   = (float*)(ws + off); off += 786432;
  float* nnT  = (float*)(ws + off); off += 786432;
  float* num  = (float*)(ws + off); off += 1024;                      // 256*4
  double* bden = (double*)(ws + off); off += 6144;                    // 3*256*8
  double* qden = (double*)(ws + off); off += 2048;                    // 256*8
  unsigned long long* gmax = (unsigned long long*)(ws + off); off += 2048;

  init_kernel<<<1, 256, 0, stream>>>(gmax, bden);
  prep_kernel<<<1024, 256, 0, stream>>>(V, L, orgb, augs);
  sim_argmax_kernel<<<S_SUP / 128, 512, 0, stream>>>(orgb, sf, gmax);
  nn_kernel<<<B_ROWS, 256, 0, stream>>>(gmax, sf, augs, nn, nnT, num);
  bden_kernel<<<192, 256, 0, stream>>>(augs, nnT, bden);
  queue_kernel<<<B_ROWS, 256, 0, stream>>>(gps, sgps, sf, nn, qden);
  loss_kernel<<<1, 256, 0, stream>>>(num, bden, qden, out);
}